// Round 10
// baseline (125.784 us; speedup 1.0000x reference)
//
#include <hip/hip_runtime.h>
#include <hip/hip_bf16.h>
#include <stdint.h>

typedef __attribute__((ext_vector_type(8))) __bf16 bf16x8;
typedef __attribute__((ext_vector_type(4))) float f32x4;

static __device__ __forceinline__ unsigned short f2bf(float f) {
    unsigned int u = __float_as_uint(f);
    unsigned int r = (u + 0x7fffu + ((u >> 16) & 1u)) >> 16;
    return (unsigned short)r;
}

// ---------------- Kernel 1: 2:4 prune + variance-ratio scale (+ weight conv) ----------------
// Blocks 0..32767: one row of x each. Blocks 32768..33791: weight fp32->bf16.
__global__ __launch_bounds__(256) void prune_scale_kernel(
    const float* __restrict__ x, unsigned short* __restrict__ a,
    const float* __restrict__ wsrc, unsigned short* __restrict__ wdst)
{
    const int bid = blockIdx.x;
    const int t = threadIdx.x;

    if (bid >= 32768) {                        // ---- weight conversion part ----
        const int i = (bid - 32768) * 256 + t; // 4 elems per thread
        const float4 v = ((const float4*)wsrc)[i];
        ushort4 o;
        o.x = f2bf(v.x); o.y = f2bf(v.y); o.z = f2bf(v.z); o.w = f2bf(v.w);
        ((ushort4*)wdst)[i] = o;
        return;
    }

    const int row = bid;
    const float4 g = ((const float4*)(x + (size_t)row * 1024))[t];

    const float a0 = fabsf(g.x), a1 = fabsf(g.y), a2 = fabsf(g.z), a3 = fabsf(g.w);
    // rank via stable tie-break (lower index wins) -- matches jax.lax.top_k
    const int r0 = (a1 > a0) + (a2 > a0) + (a3 > a0);
    const int r1 = (a0 >= a1) + (a2 > a1) + (a3 > a1);
    const int r2 = (a0 >= a2) + (a1 >= a2) + (a3 > a2);
    const int r3 = (a0 >= a3) + (a1 >= a3) + (a2 >= a3);
    const float p0 = (r0 < 2) ? g.x : 0.0f;
    const float p1 = (r1 < 2) ? g.y : 0.0f;
    const float p2 = (r2 < 2) ? g.z : 0.0f;
    const float p3 = (r3 < 2) ? g.w : 0.0f;

    float sx  = g.x + g.y + g.z + g.w;
    float sxx = g.x*g.x + g.y*g.y + g.z*g.z + g.w*g.w;
    float sp  = p0 + p1 + p2 + p3;
    float spp = p0*p0 + p1*p1 + p2*p2 + p3*p3;

    #pragma unroll
    for (int off = 32; off > 0; off >>= 1) {
        sx  += __shfl_down(sx,  off);
        sxx += __shfl_down(sxx, off);
        sp  += __shfl_down(sp,  off);
        spp += __shfl_down(spp, off);
    }
    __shared__ float red[4][4];
    __shared__ float vsh;
    const int lane = t & 63, w = t >> 6;
    if (lane == 0) { red[w][0] = sx; red[w][1] = sxx; red[w][2] = sp; red[w][3] = spp; }
    __syncthreads();
    if (t == 0) {
        float SX = 0.f, SXX = 0.f, SP = 0.f, SPP = 0.f;
        #pragma unroll
        for (int i = 0; i < 4; ++i) { SX += red[i][0]; SXX += red[i][1]; SP += red[i][2]; SPP += red[i][3]; }
        const float D = 1024.0f, DM1 = 1023.0f;
        const float var_x = (SXX - SX * SX / D) / DM1;
        float var_p = (SPP - SP * SP / D) / DM1;
        var_p = fmaxf(var_p, 1e-9f);
        vsh = sqrtf(var_x / var_p);
    }
    __syncthreads();
    const float v = vsh;

    ushort4 o;
    o.x = f2bf(v * p0); o.y = f2bf(v * p1); o.z = f2bf(v * p2); o.w = f2bf(v * p3);
    ((ushort4*)(a + (size_t)row * 1024))[t] = o;
}

// ---------------- Kernel 2: persistent 2-tile 256x256x64 bf16 GEMM (B^T), fp32 out ----------------
// Round-9-proven LDS layout/swizzle/readers. Changes:
//  (a) super-phases: 2 per K-tile (32 MFMA each) -> 4 barriers + 2 lgkm drains per tile (was 8/4).
//      FIFO (loads): invariant 4 outstanding entering each sp; VMW(4) at sp0 retires kh1(tt),
//      VMW(4) at sp1 retires kh0(tt+1).
//  (b) persistent pairing: 256 blocks, each does (tile_m, 2p) then (tile_m, 2p+1).
//      A-pass tt=15 wrap-staging IS the B-pass prologue (same A; B pointer cselect-redirected).
//      Between passes: VMW(0); barrier; C-epilogue-A; B-pass with tt=0 sp0-VMW skipped.
#define KD 1024
#define ND 1024

#define GLL16(gp, lp)                                                          \
    __builtin_amdgcn_global_load_lds(                                          \
        (const __attribute__((address_space(1))) void*)(gp),                   \
        (__attribute__((address_space(3))) void*)(lp), 16, 0, 0)

#define VMW(n) asm volatile("s_waitcnt vmcnt(" #n ")" ::: "memory")

#define ASTAGE(bufx, kh, kt) {                                                 \
    const unsigned short* _s = aG + (size_t)(kt) * 64 + (kh) * 32;             \
    char* _dp = smem + (bufx) * 32768 + (kh) * 16384 + w * 1024;               \
    GLL16(_s, _dp); GLL16(_s + 128 * KD, _dp + 8192); }

#define BSTG(bg, bufx, kh, kt) {                                               \
    const unsigned short* _s = (bg) + (size_t)(kt) * 64 + (kh) * 32;           \
    char* _dp = smem + 65536 + (bufx) * 32768 + (kh) * 16384 + w * 1024;       \
    GLL16(_s, _dp); GLL16(_s + 128 * KD, _dp + 8192); }

// super-phase: read all A (both mh) + B frags for k-half ks; stage; wait; barrier;
// 32 MFMA; barrier.
#define SUPER(bufx, ks, STAGE_STMT, VM_STMT) {                                 \
    bf16x8 af[8], bk[4];                                                       \
    const char* _ab = smem + (bufx) * 32768 + (ks) * 16384 + aR0;              \
    af[0] = *(const bf16x8*)(_ab);                                             \
    af[1] = *(const bf16x8*)(_ab + 1024);                                      \
    af[2] = *(const bf16x8*)(_ab + 2048);                                      \
    af[3] = *(const bf16x8*)(_ab + 3072);                                      \
    af[4] = *(const bf16x8*)(_ab + 4096);                                      \
    af[5] = *(const bf16x8*)(_ab + 5120);                                      \
    af[6] = *(const bf16x8*)(_ab + 6144);                                      \
    af[7] = *(const bf16x8*)(_ab + 7168);                                      \
    const char* _bb = smem + 65536 + (bufx) * 32768 + (ks) * 16384 + bR0;      \
    bk[0] = *(const bf16x8*)(_bb);                                             \
    bk[1] = *(const bf16x8*)(_bb + 1024);                                      \
    bk[2] = *(const bf16x8*)(_bb + 2048);                                      \
    bk[3] = *(const bf16x8*)(_bb + 3072);                                      \
    STAGE_STMT;                                                                \
    VM_STMT;                                                                   \
    __builtin_amdgcn_s_barrier();                                              \
    asm volatile("s_waitcnt lgkmcnt(0)" ::: "memory");                         \
    __builtin_amdgcn_s_setprio(1);                                             \
    _Pragma("unroll") for (int _i = 0; _i < 8; ++_i)                           \
      _Pragma("unroll") for (int _n = 0; _n < 4; ++_n)                         \
        acc[_i][_n] = __builtin_amdgcn_mfma_f32_16x16x32_bf16(                 \
            af[_i], bk[_n], acc[_i][_n], 0, 0, 0);                             \
    __builtin_amdgcn_s_setprio(0);                                             \
    __builtin_amdgcn_s_barrier(); }

#define EPILOGUE(tn) {                                                         \
    float* Cp = C + (size_t)(tile_m * 256 + wm * 128 + ((l >> 4) * 4)) * ND    \
                  + (tn) * 256 + wn * 64 + (l & 15);                           \
    _Pragma("unroll") for (int _m = 0; _m < 8; ++_m)                           \
      _Pragma("unroll") for (int _n = 0; _n < 4; ++_n)                         \
        _Pragma("unroll") for (int _j = 0; _j < 4; ++_j)                       \
          Cp[(size_t)(_m * 16 + _j) * ND + _n * 16] = acc[_m][_n][_j]; }

__global__ __launch_bounds__(512, 2) void gemm256_kernel(
    const unsigned short* __restrict__ A,   // [32768][1024] bf16
    const unsigned short* __restrict__ B,   // [1024][1024] bf16 (W row-major = B^T)
    float* __restrict__ C)                  // [32768][1024] f32
{
    __shared__ char smem[131072];

    const int t = threadIdx.x;
    const int w = t >> 6, l = t & 63;
    const int wm = w >> 2, wn = w & 3;

    // 256 blocks; XCD swizzle (256 = 8 x 32, bijective). Same-tile_m pair adjacent on XCD.
    const int bid = blockIdx.x;
    const int swz = (bid & 7) * 32 + (bid >> 3);
    const int tile_m = swz >> 1;              // 0..127
    const int npair  = swz & 1;               // n-tiles {0,1} or {2,3}
    const int tn0 = npair * 2, tn1 = npair * 2 + 1;

    // staging source (per-lane, pre-swizzled 16B granule)
    const int r0 = w * 16 + (l >> 2);
    const int gsrc = (l & 3) ^ ((l >> 3) & 3);
    const unsigned short* aG  = A + (size_t)(tile_m * 256 + r0) * KD + gsrc * 8;
    const unsigned short* bGa = B + (size_t)(tn0 * 256 + r0) * KD + gsrc * 8;
    const unsigned short* bGn = B + (size_t)(tn1 * 256 + r0) * KD + gsrc * 8;

    // reader bases (byte offsets into smem)
    const int gq = (l >> 4) ^ ((l >> 1) & 3);
    const int aR0 = (wm * 128 + (l & 15)) * 64 + gq * 16;
    const int bR0 = (wn * 64 + (l & 15)) * 64 + gq * 16;

    f32x4 acc[8][4] = {};

    // ---- prologue (tile A, K-tile 0): [Ak0,Bk0,Ak1,Bk1]; retire first two ----
    ASTAGE(0, 0, 0);  BSTG(bGa, 0, 0, 0);
    ASTAGE(0, 1, 0);  BSTG(bGa, 0, 1, 0);
    VMW(4);
    __builtin_amdgcn_s_barrier();

    // ---- PASS A ---- (tt=15 stages K-tile-0 of pass B: A identical, B redirected)
    for (int tt = 0; tt < 16; ++tt) {
        const int bc = tt & 1, bn = bc ^ 1;
        const int T1 = (tt + 1) & 15;
        const unsigned short* bT = (tt == 15) ? bGn : bGa;
        SUPER(bc, 0, { ASTAGE(bn, 0, T1); BSTG(bT, bn, 0, T1); }, VMW(4));
        SUPER(bc, 1, { ASTAGE(bn, 1, T1); BSTG(bT, bn, 1, T1); }, VMW(4));
    }
    // Q = [Ak1_B(0), Bk1_B(0)] : retire now (1 sp old), before stores enter the FIFO
    VMW(0);
    __syncthreads();

    EPILOGUE(tn0);                            // C stores for tile A (enter vmcnt FIFO)

    #pragma unroll
    for (int _m = 0; _m < 8; ++_m)
        #pragma unroll
        for (int _n = 0; _n < 4; ++_n)
            acc[_m][_n] = (f32x4){0.f, 0.f, 0.f, 0.f};

    // ---- PASS B ---- tt=0 peeled: sp0 has no VMW (its targets were pre-drained);
    // sp1's VMW(4) retires stores (L2-ack) + nothing else -- the accepted overlap cost.
    {
        SUPER(0, 0, { ASTAGE(1, 0, 1); BSTG(bGn, 1, 0, 1); },       );
        SUPER(0, 1, { ASTAGE(1, 1, 1); BSTG(bGn, 1, 1, 1); }, VMW(4));
    }
    for (int tt = 1; tt < 16; ++tt) {
        const int bc = tt & 1, bn = bc ^ 1;
        const int T1 = (tt + 1) & 15;
        SUPER(bc, 0, { ASTAGE(bn, 0, T1); BSTG(bGn, bn, 0, T1); }, VMW(4));
        SUPER(bc, 1, { ASTAGE(bn, 1, T1); BSTG(bGn, bn, 1, T1); }, VMW(4));
    }
    VMW(0);

    EPILOGUE(tn1);                            // C stores for tile B
}

extern "C" void kernel_launch(void* const* d_in, const int* in_sizes, int n_in,
                              void* d_out, int out_size, void* d_ws, size_t ws_size,
                              hipStream_t stream) {
    const float* x  = (const float*)d_in[0];   // [4,8192,1024] fp32
    const float* wt = (const float*)d_in[1];   // [1024,1024] fp32
    float* out = (float*)d_out;                // [4,8192,1024] fp32

    unsigned short* Abf = (unsigned short*)d_ws;                    // 64 MiB
    unsigned short* Wbf = Abf + (size_t)32768 * 1024;               // +2 MiB

    prune_scale_kernel<<<33792, 256, 0, stream>>>(x, Abf, wt, Wbf);
    gemm256_kernel<<<256, 512, 0, stream>>>(Abf, Wbf, out);
}